// Round 1
// baseline (796.283 us; speedup 1.0000x reference)
//
#include <hip/hip_runtime.h>

// FeatureOctree, level-phased: one kernel launch per level so each level's
// 128 MB feature table fits in the 256 MB Infinity Cache (LLC).
// Fused 3-level version thrashed the LLC (384 MB combined working set):
// FETCH_SIZE showed ~1.58 GB (= no-cache ideal) despite 4x average row reuse.
//
// 4 threads per point; lane `sub` in [0,4) owns float4 slice `sub` of the
// 16-dim feature. x/idx/out traffic is marked non-temporal to keep the LLC
// dedicated to the feature table.

typedef float v4f __attribute__((ext_vector_type(4)));
typedef int   v4i __attribute__((ext_vector_type(4)));

template <bool ACCUM>
__global__ __launch_bounds__(256) void octree_level_kernel(
    const float* __restrict__ x,
    const v4f* __restrict__ feat,
    const int* __restrict__ idx,
    v4f* __restrict__ out,
    float scale,
    int n_pts)
{
    long long tid = (long long)blockIdx.x * blockDim.x + threadIdx.x;
    long long pt = tid >> 2;
    int sub = (int)(tid & 3);
    if (pt >= n_pts) return;

    // Streaming reads: non-temporal (no reuse; don't pollute LLC).
    float xv = __builtin_nontemporal_load(x + pt * 3 + 0);
    float yv = __builtin_nontemporal_load(x + pt * 3 + 1);
    float zv = __builtin_nontemporal_load(x + pt * 3 + 2);

    // coords(level) = 2^level * (x*0.5 + 0.5)
    float cx = scale * (xv * 0.5f + 0.5f);
    float cy = scale * (yv * 0.5f + 0.5f);
    float cz = scale * (zv * 0.5f + 0.5f);

    float dx = cx - floorf(cx);
    float dy = cy - floorf(cy);
    float dz = cz - floorf(cz);
    // t = 3d^2 - 2d^3
    float tx = dx * dx * (3.0f - 2.0f * dx);
    float ty = dy * dy * (3.0f - 2.0f * dy);
    float tz = dz * dz * (3.0f - 2.0f * dz);
    float ux = 1.0f - tx, uy = 1.0f - ty, uz = 1.0f - tz;

    float p[8];
    p[0] = ux * uy * uz;
    p[1] = ux * uy * tz;
    p[2] = ux * ty * uz;
    p[3] = ux * ty * tz;
    p[4] = tx * uy * uz;
    p[5] = tx * uy * tz;
    p[6] = tx * ty * uz;
    p[7] = tx * ty * tz;

    // idx row: 8 int32, 32B-aligned -> two int4 non-temporal loads
    const v4i* iv = (const v4i*)(idx + pt * 8);
    v4i ia = __builtin_nontemporal_load(iv);
    v4i ib = __builtin_nontemporal_load(iv + 1);
    int id[8] = { ia.x, ia.y, ia.z, ia.w, ib.x, ib.y, ib.z, ib.w };

    v4f acc;
    if (ACCUM) {
        acc = __builtin_nontemporal_load(out + pt * 4 + sub);
    } else {
        acc = (v4f){0.0f, 0.0f, 0.0f, 0.0f};
    }

    // Feature gathers: normal (cached) loads — the whole point is LLC reuse.
#pragma unroll
    for (int k = 0; k < 8; ++k) {
        v4f g = feat[(long long)id[k] * 4 + sub];
        acc.x = fmaf(p[k], g.x, acc.x);
        acc.y = fmaf(p[k], g.y, acc.y);
        acc.z = fmaf(p[k], g.z, acc.z);
        acc.w = fmaf(p[k], g.w, acc.w);
    }

    __builtin_nontemporal_store(acc, out + pt * 4 + sub);
}

extern "C" void kernel_launch(void* const* d_in, const int* in_sizes, int n_in,
                              void* d_out, int out_size, void* d_ws, size_t ws_size,
                              hipStream_t stream) {
    const float* x  = (const float*)d_in[0];
    const v4f*   f0 = (const v4f*)d_in[1];
    const v4f*   f1 = (const v4f*)d_in[2];
    const v4f*   f2 = (const v4f*)d_in[3];
    const int*   i0 = (const int*)d_in[4];
    const int*   i1 = (const int*)d_in[5];
    const int*   i2 = (const int*)d_in[6];
    v4f* out = (v4f*)d_out;

    int n_pts = in_sizes[0] / 3;
    long long total = (long long)n_pts * 4;
    int block = 256;
    int grid = (int)((total + block - 1) / block);

    // One pass per level: the per-level 128 MB table fits the 256 MB LLC,
    // turning ~3/4 of the random 64B gathers into LLC hits.
    octree_level_kernel<false><<<grid, block, 0, stream>>>(x, f0, i0, out, 4096.0f, n_pts); // level 12
    octree_level_kernel<true ><<<grid, block, 0, stream>>>(x, f1, i1, out, 2048.0f, n_pts); // level 11
    octree_level_kernel<true ><<<grid, block, 0, stream>>>(x, f2, i2, out, 1024.0f, n_pts); // level 10
}

// Round 2
// 787.009 us; speedup vs baseline: 1.0118x; 1.0118x over previous
//
#include <hip/hip_runtime.h>

// FeatureOctree, fused single-pass (reverted from level-phased after the R1
// experiment showed the 256 MB LLC does NOT retain a 128 MB per-level table
// under fully-random 64B gathers: per-pass FETCH stayed ~86% of the no-cache
// ideal and total EA traffic went UP due to the out read-modify-write).
//
// Structural regime: ~1.64 GB/iter of compulsory random-64B traffic moving at
// the measured ~3.2-3.3 TB/s random-access ceiling (52% of the 6.3 TB/s
// streaming ceiling). VALUBusy 5%, occupancy 80%, concurrency ample -> pure
// memory-throughput bound on irreducible traffic.
//
// 4 threads per point; lane `sub` in [0,4) owns float4 slice `sub` of the
// 16-dim feature. Streaming operands (x, idx, out) use non-temporal hints so
// cache capacity stays dedicated to feature lines.

typedef float v4f __attribute__((ext_vector_type(4)));
typedef int   v4i __attribute__((ext_vector_type(4)));

__device__ __forceinline__ void accum_level(
    long long pt, int sub, float cx, float cy, float cz,
    const v4f* __restrict__ feat, const int* __restrict__ idx,
    v4f& acc)
{
    float dx = cx - floorf(cx);
    float dy = cy - floorf(cy);
    float dz = cz - floorf(cz);
    // t = 3d^2 - 2d^3
    float tx = dx * dx * (3.0f - 2.0f * dx);
    float ty = dy * dy * (3.0f - 2.0f * dy);
    float tz = dz * dz * (3.0f - 2.0f * dz);
    float ux = 1.0f - tx, uy = 1.0f - ty, uz = 1.0f - tz;

    float p[8];
    p[0] = ux * uy * uz;
    p[1] = ux * uy * tz;
    p[2] = ux * ty * uz;
    p[3] = ux * ty * tz;
    p[4] = tx * uy * uz;
    p[5] = tx * uy * tz;
    p[6] = tx * ty * uz;
    p[7] = tx * ty * tz;

    // idx row: 8 int32, 32B-aligned -> two int4 non-temporal loads
    // (4 lanes of one point read identical addresses -> HW broadcast, no
    // extra traffic).
    const v4i* iv = (const v4i*)(idx + pt * 8);
    v4i ia = __builtin_nontemporal_load(iv);
    v4i ib = __builtin_nontemporal_load(iv + 1);
    int id[8] = { ia.x, ia.y, ia.z, ia.w, ib.x, ib.y, ib.z, ib.w };

    // Feature gathers: normal (cached) loads. 4 consecutive lanes cover one
    // 64B row -> one line request per (point, corner).
#pragma unroll
    for (int k = 0; k < 8; ++k) {
        v4f g = feat[(long long)id[k] * 4 + sub];
        acc.x = fmaf(p[k], g.x, acc.x);
        acc.y = fmaf(p[k], g.y, acc.y);
        acc.z = fmaf(p[k], g.z, acc.z);
        acc.w = fmaf(p[k], g.w, acc.w);
    }
}

__global__ __launch_bounds__(256) void FeatureOctree_74749610820348_kernel(
    const float* __restrict__ x,
    const v4f* __restrict__ f0,
    const v4f* __restrict__ f1,
    const v4f* __restrict__ f2,
    const int* __restrict__ i0,
    const int* __restrict__ i1,
    const int* __restrict__ i2,
    v4f* __restrict__ out,
    int n_pts)
{
    long long tid = (long long)blockIdx.x * blockDim.x + threadIdx.x;
    long long pt = tid >> 2;
    int sub = (int)(tid & 3);
    if (pt >= n_pts) return;

    float xv = __builtin_nontemporal_load(x + pt * 3 + 0);
    float yv = __builtin_nontemporal_load(x + pt * 3 + 1);
    float zv = __builtin_nontemporal_load(x + pt * 3 + 2);

    // base = x*0.5 + 0.5 ; coords(level) = 2^level * base
    float bx = xv * 0.5f + 0.5f;
    float by = yv * 0.5f + 0.5f;
    float bz = zv * 0.5f + 0.5f;

    v4f acc = (v4f){0.0f, 0.0f, 0.0f, 0.0f};

    accum_level(pt, sub, 4096.0f * bx, 4096.0f * by, 4096.0f * bz, f0, i0, acc); // level 12
    accum_level(pt, sub, 2048.0f * bx, 2048.0f * by, 2048.0f * bz, f1, i1, acc); // level 11
    accum_level(pt, sub, 1024.0f * bx, 1024.0f * by, 1024.0f * bz, f2, i2, acc); // level 10

    __builtin_nontemporal_store(acc, out + pt * 4 + sub);
}

extern "C" void kernel_launch(void* const* d_in, const int* in_sizes, int n_in,
                              void* d_out, int out_size, void* d_ws, size_t ws_size,
                              hipStream_t stream) {
    const float* x  = (const float*)d_in[0];
    const v4f*   f0 = (const v4f*)d_in[1];
    const v4f*   f1 = (const v4f*)d_in[2];
    const v4f*   f2 = (const v4f*)d_in[3];
    const int*   i0 = (const int*)d_in[4];
    const int*   i1 = (const int*)d_in[5];
    const int*   i2 = (const int*)d_in[6];
    v4f* out = (v4f*)d_out;

    int n_pts = in_sizes[0] / 3;
    long long total = (long long)n_pts * 4;
    int block = 256;
    int grid = (int)((total + block - 1) / block);

    FeatureOctree_74749610820348_kernel<<<grid, block, 0, stream>>>(
        x, f0, f1, f2, i0, i1, i2, out, n_pts);
}